// Round 1
// baseline (108.225 us; speedup 1.0000x reference)
//
#include <hip/hip_runtime.h>
#include <hip/hip_bf16.h>
#include <stddef.h>

#define R_ 4
#define J_ 6
#define N_ 4096
#define DI_ 128
#define DO_ 64

typedef __bf16 bf16x8 __attribute__((ext_vector_type(8)));
typedef float f32x4 __attribute__((ext_vector_type(4)));

__device__ __forceinline__ bf16x8 cvt8(f32x4 a, f32x4 b) {
    bf16x8 r;
    r[0] = (__bf16)a[0]; r[1] = (__bf16)a[1]; r[2] = (__bf16)a[2]; r[3] = (__bf16)a[3];
    r[4] = (__bf16)b[0]; r[5] = (__bf16)b[1]; r[6] = (__bf16)b[2]; r[7] = (__bf16)b[3];
    return r;
}

// ---------------------------------------------------------------------------
// Kernel 1: yT[r][o][m] = coef[r] * sum_d fc_w[r][o][d] * x[r][m][d]   (bf16)
// MFMA: M-dim = o (A = fc_w rows, k-contiguous), N-dim = m (B = x rows,
// k-contiguous), K = d. One block = one (r, 64-m tile); wave w owns o-quad.
// ---------------------------------------------------------------------------
__global__ __launch_bounds__(256) void k_prep(const float* __restrict__ theta,
                                              const float* __restrict__ tt,
                                              const float* __restrict__ x,
                                              const float* __restrict__ fcw,
                                              __bf16* __restrict__ Y)
{
    const int b = blockIdx.x;
    const int r = b >> 6;
    const int m0 = (b & 63) << 6;
    const int tid = threadIdx.x;
    const int w = tid >> 6, l = tid & 63, lg = l >> 4, lr = l & 15;

    float coef = 0.f;
    #pragma unroll
    for (int j = 0; j < J_; ++j) coef += theta[r * J_ + j] * tt[r * J_ + j];

    const float* wp  = fcw + ((size_t)r * DO_ + w * 16 + lr) * DI_ + lg * 8;
    const float* xp0 = x   + ((size_t)r * N_  + m0     + lr) * DI_ + lg * 8;

    f32x4 acc[4];
    #pragma unroll
    for (int mt = 0; mt < 4; ++mt) acc[mt] = (f32x4)0.0f;

    #pragma unroll
    for (int s = 0; s < 4; ++s) {
        bf16x8 af = cvt8(*(const f32x4*)(wp + s * 32), *(const f32x4*)(wp + s * 32 + 4));
        #pragma unroll
        for (int mt = 0; mt < 4; ++mt) {
            const float* xp = xp0 + (size_t)mt * 16 * DI_ + s * 32;
            bf16x8 bf = cvt8(*(const f32x4*)xp, *(const f32x4*)(xp + 4));
            acc[mt] = __builtin_amdgcn_mfma_f32_16x16x32_bf16(af, bf, acc[mt], 0, 0, 0);
        }
    }

    // D layout: col (=m) = lane&15, row (=o-in-tile) = (lane>>4)*4 + reg
    #pragma unroll
    for (int mt = 0; mt < 4; ++mt) {
        #pragma unroll
        for (int i = 0; i < 4; ++i) {
            const int o = w * 16 + lg * 4 + i;
            Y[((size_t)r * DO_ + o) * N_ + m0 + mt * 16 + lr] = (__bf16)(coef * acc[mt][i]);
        }
    }
}

// ---------------------------------------------------------------------------
// Kernel 2: u[r][n][o] = prelu( sum_m a[r][n][m] * y[r][m][o] + fc_b[r][o] )
// One block = 16 rows of one relation, full 64 cols. 4 waves K-split the
// m-reduction (1024 each), LDS reduce, fused epilogue. A: fp32->bf16 in regs.
// ---------------------------------------------------------------------------
__global__ __launch_bounds__(256, 4) void k_diff(const float* __restrict__ A,
                                                 const __bf16* __restrict__ Y,
                                                 const float* __restrict__ fcb,
                                                 const float* __restrict__ p0p,
                                                 float* __restrict__ U)
{
    const int b = blockIdx.x;
    const int r = b >> 8;
    const int n0 = (b & 255) << 4;
    const int tid = threadIdx.x;
    const int w = tid >> 6, l = tid & 63, lg = l >> 4, lr = l & 15;

    const float*  ap  = A + ((size_t)r * N_ + n0 + lr) * N_ + (size_t)w * 1024 + lg * 8;
    const __bf16* yb0 = Y + ((size_t)r * DO_ + lr) * N_ + (size_t)w * 1024 + lg * 8;

    f32x4 acc[4];
    #pragma unroll
    for (int ot = 0; ot < 4; ++ot) acc[ot] = (f32x4)0.0f;

    #pragma unroll 4
    for (int s = 0; s < 32; ++s) {
        const float* a8 = ap + s * 32;
        bf16x8 af = cvt8(*(const f32x4*)a8, *(const f32x4*)(a8 + 4));
        #pragma unroll
        for (int ot = 0; ot < 4; ++ot) {
            bf16x8 bf = *(const bf16x8*)(yb0 + (size_t)ot * 16 * N_ + s * 32);
            acc[ot] = __builtin_amdgcn_mfma_f32_16x16x32_bf16(af, bf, acc[ot], 0, 0, 0);
        }
    }

    // K-split reduction in LDS. Layout [wave][n(16)][o pad 68] -> 2-way max.
    __shared__ __align__(16) float red[4][16][68];
    #pragma unroll
    for (int ot = 0; ot < 4; ++ot) {
        #pragma unroll
        for (int i = 0; i < 4; ++i)
            red[w][lg * 4 + i][ot * 16 + lr] = acc[ot][i];
    }
    __syncthreads();

    const int n = tid >> 4;
    const int o = (tid & 15) << 2;
    f32x4 s4 = *(const f32x4*)&red[0][n][o];
    #pragma unroll
    for (int w2 = 1; w2 < 4; ++w2)
        s4 += *(const f32x4*)&red[w2][n][o];

    const float p0 = *p0p;
    f32x4 uv;
    #pragma unroll
    for (int j = 0; j < 4; ++j) {
        const float v = s4[j] + fcb[r * DO_ + o + j];
        uv[j] = v >= 0.f ? v : p0 * v;
    }
    *(f32x4*)&U[((size_t)r * N_ + n0 + n) * DO_ + o] = uv;
}

// ---------------------------------------------------------------------------
// Kernel 3: h[q][n][o] = prelu( sum_r conv_w[q][r] * u[r][n][o] + conv_b[q] )
// ---------------------------------------------------------------------------
__global__ __launch_bounds__(256) void k_conv(const float* __restrict__ U,
                                              const float* __restrict__ cw,
                                              const float* __restrict__ cb,
                                              const float* __restrict__ p1p,
                                              float* __restrict__ H)
{
    const size_t t = (size_t)blockIdx.x * 256 + threadIdx.x;
    const size_t base = t * 4;
    const size_t SL = (size_t)N_ * DO_;  // 262144

    f32x4 u0 = *(const f32x4*)&U[base];
    f32x4 u1 = *(const f32x4*)&U[base + SL];
    f32x4 u2 = *(const f32x4*)&U[base + 2 * SL];
    f32x4 u3 = *(const f32x4*)&U[base + 3 * SL];
    const float p1 = *p1p;

    #pragma unroll
    for (int q = 0; q < 4; ++q) {
        f32x4 hv = cw[q * 4 + 0] * u0 + cw[q * 4 + 1] * u1 +
                   cw[q * 4 + 2] * u2 + cw[q * 4 + 3] * u3;
        const float bq = cb[q];
        f32x4 ho;
        #pragma unroll
        for (int j = 0; j < 4; ++j) {
            const float v = hv[j] + bq;
            ho[j] = v >= 0.f ? v : p1 * v;
        }
        *(f32x4*)&H[q * SL + base] = ho;
    }
}

extern "C" void kernel_launch(void* const* d_in, const int* in_sizes, int n_in,
                              void* d_out, int out_size, void* d_ws, size_t ws_size,
                              hipStream_t stream)
{
    const float* theta = (const float*)d_in[0];
    const float* tt    = (const float*)d_in[1];
    const float* a     = (const float*)d_in[2];
    const float* x     = (const float*)d_in[3];
    const float* fcw   = (const float*)d_in[4];
    const float* fcb   = (const float*)d_in[5];
    const float* cw    = (const float*)d_in[6];
    const float* cb    = (const float*)d_in[7];
    const float* p0    = (const float*)d_in[8];
    const float* p1    = (const float*)d_in[9];

    float* out = (float*)d_out;
    float* H = out;                              // output 0: h  [R,N,DO]
    float* U = out + (size_t)R_ * N_ * DO_;      // output 1: u  [R,N,DO]

    // Scratch for bf16 yT [R][DO][N] (2 MB). Fall back to the h-region of
    // d_out (written last by k_conv, after k_diff consumed Y) if ws is small.
    const size_t ybytes = (size_t)R_ * DO_ * N_ * sizeof(__bf16);
    __bf16* Y = (ws_size >= ybytes) ? (__bf16*)d_ws : (__bf16*)H;

    k_prep<<<dim3(256), dim3(256), 0, stream>>>(theta, tt, x, fcw, Y);
    k_diff<<<dim3(1024), dim3(256), 0, stream>>>(a, Y, fcb, p0, U);
    k_conv<<<dim3(256), dim3(256), 0, stream>>>(U, cw, cb, p1, H);
}

// Round 3
// 76.788 us; speedup vs baseline: 1.4094x; 1.4094x over previous
//
#include <hip/hip_runtime.h>
#include <hip/hip_bf16.h>
#include <stddef.h>

#define R_ 4
#define J_ 6
#define N_ 4096
#define DI_ 128
#define DO_ 64

typedef __bf16 bf16x8 __attribute__((ext_vector_type(8)));
typedef float f32x4 __attribute__((ext_vector_type(4)));

static __device__ __forceinline__ bf16x8 cvt8(f32x4 a, f32x4 b) {
    bf16x8 r;
    r[0] = (__bf16)a[0]; r[1] = (__bf16)a[1]; r[2] = (__bf16)a[2]; r[3] = (__bf16)a[3];
    r[4] = (__bf16)b[0]; r[5] = (__bf16)b[1]; r[6] = (__bf16)b[2]; r[7] = (__bf16)b[3];
    return r;
}

// ---------------------------------------------------------------------------
// Kernel 1: y[r][o][m] = coef[r] * sum_d fc_w[r][o][d] * x[r][m][d], stored as
// pre-packed MFMA B-fragments:
//   Yf[r][kb=m>>5][ot=o>>4][lane=(o&15)+16*((m&31)>>3)][j=m&7]   (bf16)
// so each k_diff B-operand load is ONE fully-coalesced 1KB wave instruction.
// ---------------------------------------------------------------------------
__global__ __launch_bounds__(256) void k_prep(const float* __restrict__ theta,
                                              const float* __restrict__ tt,
                                              const float* __restrict__ x,
                                              const float* __restrict__ fcw,
                                              __bf16* __restrict__ Yf)
{
    const int b = blockIdx.x;
    const int r = b >> 6;
    const int m0 = (b & 63) << 6;
    const int tid = threadIdx.x;
    const int w = tid >> 6, l = tid & 63, lg = l >> 4, lr = l & 15;

    float coef = 0.f;
    #pragma unroll
    for (int j = 0; j < J_; ++j) coef += theta[r * J_ + j] * tt[r * J_ + j];

    const float* wp  = fcw + ((size_t)r * DO_ + w * 16 + lr) * DI_ + lg * 8;
    const float* xp0 = x   + ((size_t)r * N_  + m0     + lr) * DI_ + lg * 8;

    f32x4 acc[4];
    #pragma unroll
    for (int mt = 0; mt < 4; ++mt) acc[mt] = (f32x4)0.0f;

    #pragma unroll
    for (int s = 0; s < 4; ++s) {
        bf16x8 af = cvt8(*(const f32x4*)(wp + s * 32), *(const f32x4*)(wp + s * 32 + 4));
        #pragma unroll
        for (int mt = 0; mt < 4; ++mt) {
            const float* xp = xp0 + (size_t)mt * 16 * DI_ + s * 32;
            bf16x8 bf = cvt8(*(const f32x4*)xp, *(const f32x4*)(xp + 4));
            acc[mt] = __builtin_amdgcn_mfma_f32_16x16x32_bf16(af, bf, acc[mt], 0, 0, 0);
        }
    }

    // acc[mt][i] = y[o = w*16 + lg*4 + i][m = m0 + mt*16 + lr]
    __bf16* Yr = Yf + (size_t)r * (DO_ * N_);
    #pragma unroll
    for (int mt = 0; mt < 4; ++mt) {
        const int kb = (m0 >> 5) + (mt >> 1);           // m>>5
        const int hi = ((mt & 1) << 1) + (lr >> 3);     // (m&31)>>3
        const int j  = lr & 7;                          // m&7
        #pragma unroll
        for (int i = 0; i < 4; ++i) {
            const int lanep = lg * 4 + i + (hi << 4);   // (o&15)+16*((m&31)>>3)
            Yr[((size_t)(kb * 4 + w) * 64 + lanep) * 8 + j] = (__bf16)(coef * acc[mt][i]);
        }
    }
}

// ---------------------------------------------------------------------------
// Kernel 2: u[r][n][o] = prelu( sum_m a[r][n][m] * y[r][m][o] + fc_b[r][o] )
// EXACT round-1 structure (passed): one block = 16 n-rows, 4 waves K-split the
// m-reduction, LDS reduce, fused epilogue. ONLY the Y-loads changed: packed
// fragments -> one contiguous 1KB load per B operand (was 16 scattered segs).
// ---------------------------------------------------------------------------
__global__ __launch_bounds__(256, 4) void k_diff(const float* __restrict__ A,
                                                 const __bf16* __restrict__ Yf,
                                                 const float* __restrict__ fcb,
                                                 const float* __restrict__ p0p,
                                                 float* __restrict__ U)
{
    const int b = blockIdx.x;
    const int r = b >> 8;
    const int n0 = (b & 255) << 4;
    const int tid = threadIdx.x;
    const int w = tid >> 6, l = tid & 63, lg = l >> 4, lr = l & 15;

    const float* ap = A + ((size_t)r * N_ + n0 + lr) * N_ + (size_t)w * 1024 + lg * 8;
    // wave w covers kb = w*32 + s; fragment base for lane l:
    const __bf16* yb0 = Yf + (size_t)r * (DO_ * N_) + (size_t)w * 32 * 2048 + (size_t)l * 8;

    f32x4 acc[4];
    #pragma unroll
    for (int ot = 0; ot < 4; ++ot) acc[ot] = (f32x4)0.0f;

    #pragma unroll 4
    for (int s = 0; s < 32; ++s) {
        const float* a8 = ap + s * 32;
        bf16x8 af = cvt8(*(const f32x4*)a8, *(const f32x4*)(a8 + 4));
        #pragma unroll
        for (int ot = 0; ot < 4; ++ot) {
            bf16x8 bf = *(const bf16x8*)(yb0 + ((size_t)s * 4 + ot) * 512);
            acc[ot] = __builtin_amdgcn_mfma_f32_16x16x32_bf16(af, bf, acc[ot], 0, 0, 0);
        }
    }

    // K-split reduction in LDS. Layout [wave][n(16)][o pad 68] -> 2-way max.
    __shared__ __align__(16) float red[4][16][68];
    #pragma unroll
    for (int ot = 0; ot < 4; ++ot) {
        #pragma unroll
        for (int i = 0; i < 4; ++i)
            red[w][lg * 4 + i][ot * 16 + lr] = acc[ot][i];
    }
    __syncthreads();

    const int n = tid >> 4;
    const int o = (tid & 15) << 2;
    f32x4 s4 = *(const f32x4*)&red[0][n][o];
    #pragma unroll
    for (int w2 = 1; w2 < 4; ++w2)
        s4 += *(const f32x4*)&red[w2][n][o];

    const float p0 = *p0p;
    f32x4 uv;
    #pragma unroll
    for (int j = 0; j < 4; ++j) {
        const float v = s4[j] + fcb[r * DO_ + o + j];
        uv[j] = v >= 0.f ? v : p0 * v;
    }
    *(f32x4*)&U[((size_t)r * N_ + n0 + n) * DO_ + o] = uv;
}

// ---------------------------------------------------------------------------
// Kernel 3: h[q][n][o] = prelu( sum_r conv_w[q][r] * u[r][n][o] + conv_b[q] )
// ---------------------------------------------------------------------------
__global__ __launch_bounds__(256) void k_conv(const float* __restrict__ U,
                                              const float* __restrict__ cw,
                                              const float* __restrict__ cb,
                                              const float* __restrict__ p1p,
                                              float* __restrict__ H)
{
    const size_t t = (size_t)blockIdx.x * 256 + threadIdx.x;
    const size_t base = t * 4;
    const size_t SL = (size_t)N_ * DO_;  // 262144

    f32x4 u0 = *(const f32x4*)&U[base];
    f32x4 u1 = *(const f32x4*)&U[base + SL];
    f32x4 u2 = *(const f32x4*)&U[base + 2 * SL];
    f32x4 u3 = *(const f32x4*)&U[base + 3 * SL];
    const float p1 = *p1p;

    #pragma unroll
    for (int qq = 0; qq < 4; ++qq) {
        f32x4 hv = cw[qq * 4 + 0] * u0 + cw[qq * 4 + 1] * u1 +
                   cw[qq * 4 + 2] * u2 + cw[qq * 4 + 3] * u3;
        const float bq = cb[qq];
        f32x4 ho;
        #pragma unroll
        for (int j = 0; j < 4; ++j) {
            const float v = hv[j] + bq;
            ho[j] = v >= 0.f ? v : p1 * v;
        }
        *(f32x4*)&H[qq * SL + base] = ho;
    }
}

extern "C" void kernel_launch(void* const* d_in, const int* in_sizes, int n_in,
                              void* d_out, int out_size, void* d_ws, size_t ws_size,
                              hipStream_t stream)
{
    const float* theta = (const float*)d_in[0];
    const float* tt    = (const float*)d_in[1];
    const float* a     = (const float*)d_in[2];
    const float* x     = (const float*)d_in[3];
    const float* fcw   = (const float*)d_in[4];
    const float* fcb   = (const float*)d_in[5];
    const float* cw    = (const float*)d_in[6];
    const float* cb    = (const float*)d_in[7];
    const float* p0    = (const float*)d_in[8];
    const float* p1    = (const float*)d_in[9];

    float* out = (float*)d_out;
    float* H = out;                              // output 0: h  [R,N,DO]
    float* U = out + (size_t)R_ * N_ * DO_;      // output 1: u  [R,N,DO]

    // bf16 fragment-packed Y (2 MB). Fall back to H region if ws is small
    // (k_conv writes H last, after k_diff consumed Y).
    const size_t ybytes = (size_t)R_ * DO_ * N_ * sizeof(__bf16);
    __bf16* Y = (ws_size >= ybytes) ? (__bf16*)d_ws : (__bf16*)H;

    k_prep<<<dim3(256), dim3(256), 0, stream>>>(theta, tt, x, fcw, Y);
    k_diff<<<dim3(1024), dim3(256), 0, stream>>>(a, Y, fcb, p0, U);
    k_conv<<<dim3(256), dim3(256), 0, stream>>>(U, cw, cb, p1, H);
}

// Round 4
// 73.079 us; speedup vs baseline: 1.4809x; 1.0508x over previous
//
#include <hip/hip_runtime.h>
#include <hip/hip_bf16.h>
#include <stddef.h>

#define R_ 4
#define J_ 6
#define N_ 4096
#define DI_ 128
#define DO_ 64

typedef __bf16 bf16x8 __attribute__((ext_vector_type(8)));
typedef __bf16 bf16x4 __attribute__((ext_vector_type(4)));
typedef float f32x4 __attribute__((ext_vector_type(4)));

static __device__ __forceinline__ bf16x8 cvt8(f32x4 a, f32x4 b) {
    bf16x8 r;
    r[0] = (__bf16)a[0]; r[1] = (__bf16)a[1]; r[2] = (__bf16)a[2]; r[3] = (__bf16)a[3];
    r[4] = (__bf16)b[0]; r[5] = (__bf16)b[1]; r[6] = (__bf16)b[2]; r[7] = (__bf16)b[3];
    return r;
}

// ---------------------------------------------------------------------------
// Kernel 1 (unchanged, verified): y as pre-packed MFMA B-fragments:
//   Yf[r][kb=m>>5][ot=o>>4][lane=(o&15)+16*((m&31)>>3)][j=m&7]   (bf16)
// ---------------------------------------------------------------------------
__global__ __launch_bounds__(256) void k_prep(const float* __restrict__ theta,
                                              const float* __restrict__ tt,
                                              const float* __restrict__ x,
                                              const float* __restrict__ fcw,
                                              __bf16* __restrict__ Yf)
{
    const int b = blockIdx.x;
    const int r = b >> 6;
    const int m0 = (b & 63) << 6;
    const int tid = threadIdx.x;
    const int w = tid >> 6, l = tid & 63, lg = l >> 4, lr = l & 15;

    float coef = 0.f;
    #pragma unroll
    for (int j = 0; j < J_; ++j) coef += theta[r * J_ + j] * tt[r * J_ + j];

    const float* wp  = fcw + ((size_t)r * DO_ + w * 16 + lr) * DI_ + lg * 8;
    const float* xp0 = x   + ((size_t)r * N_  + m0     + lr) * DI_ + lg * 8;

    f32x4 acc[4];
    #pragma unroll
    for (int mt = 0; mt < 4; ++mt) acc[mt] = (f32x4)0.0f;

    #pragma unroll
    for (int s = 0; s < 4; ++s) {
        bf16x8 af = cvt8(*(const f32x4*)(wp + s * 32), *(const f32x4*)(wp + s * 32 + 4));
        #pragma unroll
        for (int mt = 0; mt < 4; ++mt) {
            const float* xp = xp0 + (size_t)mt * 16 * DI_ + s * 32;
            bf16x8 bf = cvt8(*(const f32x4*)xp, *(const f32x4*)(xp + 4));
            acc[mt] = __builtin_amdgcn_mfma_f32_16x16x32_bf16(af, bf, acc[mt], 0, 0, 0);
        }
    }

    __bf16* Yr = Yf + (size_t)r * (DO_ * N_);
    #pragma unroll
    for (int mt = 0; mt < 4; ++mt) {
        const int kb = (m0 >> 5) + (mt >> 1);
        const int hi = ((mt & 1) << 1) + (lr >> 3);
        const int j  = lr & 7;
        #pragma unroll
        for (int i = 0; i < 4; ++i) {
            const int lanep = lg * 4 + i + (hi << 4);
            Yr[((size_t)(kb * 4 + w) * 64 + lanep) * 8 + j] = (__bf16)(coef * acc[mt][i]);
        }
    }
}

// ---------------------------------------------------------------------------
// Kernel 2: u[r][n][o] = prelu( sum_m a[r][n][m] * y[r][m][o] + fc_b[r][o] )
// Round-3 structure (block = 16 n-rows, 4 waves K-split, LDS reduce, fused
// epilogue) with ONE change: A staged through wave-private LDS.
//   - staging loads: 4-row x 256B contiguous segments (coalesced)
//   - f32 -> bf16 converted at staging (same cvt order as round 3 ->
//     bit-identical accumulation)
//   - both LDS sides swizzled with the involution byte ^= (row&7)<<4
//     (write b64 and read b128 both at structural bank minimum)
//   - wave-private buffer: producer == consumer wave, LDS ops in-order,
//     no barriers, all waits compiler-managed.
// ---------------------------------------------------------------------------
__global__ __launch_bounds__(256, 4) void k_diff(const float* __restrict__ A,
                                                 const __bf16* __restrict__ Yf,
                                                 const float* __restrict__ fcb,
                                                 const float* __restrict__ p0p,
                                                 float* __restrict__ U)
{
    const int b = blockIdx.x;
    const int r = b >> 8;
    const int n0 = (b & 255) << 4;
    const int tid = threadIdx.x;
    const int w = tid >> 6, l = tid & 63, lg = l >> 4, lr = l & 15;

    __shared__ __bf16 abuf[4][16 * 64];            // 2KB per wave, swizzled
    __shared__ __align__(16) float red[4][16][68]; // K-split reduction

    const int srow = l >> 4;            // 0..3  (staged row = 4i + srow)
    const int scol = (l & 15) * 4;      // float col within the 64-float chunk
    const float* Abl = A + ((size_t)r * N_ + n0 + srow) * N_ + w * 1024 + scol;

    // LDS write offsets (bf16 elems) for the 4 staged pieces; byte ^ (row&7)<<4
    int wo[4];
    #pragma unroll
    for (int i = 0; i < 4; ++i) {
        const int row = 4 * i + srow;
        wo[i] = row * 64 + ((((scol * 2)) ^ ((row & 7) << 4)) >> 1);
    }
    // LDS read offsets for the 2 k-subtiles of a chunk (row = lr)
    const int q = (lr & 7) << 4;
    int ro[2];
    #pragma unroll
    for (int ss = 0; ss < 2; ++ss)
        ro[ss] = lr * 64 + (((ss * 64 + lg * 16) ^ q) >> 1);

    const __bf16* yb0 = Yf + (size_t)r * (DO_ * N_) + (size_t)w * 32 * 2048 + (size_t)l * 8;

    f32x4 acc[4];
    #pragma unroll
    for (int ot = 0; ot < 4; ++ot) acc[ot] = (f32x4)0.0f;

    // prologue: load chunk 0 to regs
    f32x4 rg[4];
    #pragma unroll
    for (int i = 0; i < 4; ++i)
        rg[i] = *(const f32x4*)(Abl + (size_t)(4 * i) * N_);

    #pragma unroll 2
    for (int c = 0; c < 16; ++c) {
        // stage chunk c (cvt + swizzled ds_write_b64)
        #pragma unroll
        for (int i = 0; i < 4; ++i) {
            bf16x4 cv;
            cv[0] = (__bf16)rg[i][0]; cv[1] = (__bf16)rg[i][1];
            cv[2] = (__bf16)rg[i][2]; cv[3] = (__bf16)rg[i][3];
            *(bf16x4*)&abuf[w][wo[i]] = cv;
        }
        // prefetch chunk c+1
        if (c < 15) {
            #pragma unroll
            for (int i = 0; i < 4; ++i)
                rg[i] = *(const f32x4*)(Abl + (size_t)(4 * i) * N_ + (c + 1) * 64);
        }
        // compute the 2 k-subtiles of chunk c
        #pragma unroll
        for (int ss = 0; ss < 2; ++ss) {
            bf16x8 af = *(const bf16x8*)&abuf[w][ro[ss]];
            const __bf16* yb = yb0 + (size_t)(c * 2 + ss) * 4 * 512;
            #pragma unroll
            for (int ot = 0; ot < 4; ++ot) {
                bf16x8 bf = *(const bf16x8*)(yb + (size_t)ot * 512);
                acc[ot] = __builtin_amdgcn_mfma_f32_16x16x32_bf16(af, bf, acc[ot], 0, 0, 0);
            }
        }
    }

    // K-split reduction in LDS (identical to round 3)
    #pragma unroll
    for (int ot = 0; ot < 4; ++ot) {
        #pragma unroll
        for (int i = 0; i < 4; ++i)
            red[w][lg * 4 + i][ot * 16 + lr] = acc[ot][i];
    }
    __syncthreads();

    const int n = tid >> 4;
    const int o = (tid & 15) << 2;
    f32x4 s4 = *(const f32x4*)&red[0][n][o];
    #pragma unroll
    for (int w2 = 1; w2 < 4; ++w2)
        s4 += *(const f32x4*)&red[w2][n][o];

    const float p0 = *p0p;
    f32x4 uv;
    #pragma unroll
    for (int j = 0; j < 4; ++j) {
        const float v = s4[j] + fcb[r * DO_ + o + j];
        uv[j] = v >= 0.f ? v : p0 * v;
    }
    *(f32x4*)&U[((size_t)r * N_ + n0 + n) * DO_ + o] = uv;
}

// ---------------------------------------------------------------------------
// Kernel 3 (unchanged): h = prelu(conv_w @ u + conv_b)
// ---------------------------------------------------------------------------
__global__ __launch_bounds__(256) void k_conv(const float* __restrict__ U,
                                              const float* __restrict__ cw,
                                              const float* __restrict__ cb,
                                              const float* __restrict__ p1p,
                                              float* __restrict__ H)
{
    const size_t t = (size_t)blockIdx.x * 256 + threadIdx.x;
    const size_t base = t * 4;
    const size_t SL = (size_t)N_ * DO_;  // 262144

    f32x4 u0 = *(const f32x4*)&U[base];
    f32x4 u1 = *(const f32x4*)&U[base + SL];
    f32x4 u2 = *(const f32x4*)&U[base + 2 * SL];
    f32x4 u3 = *(const f32x4*)&U[base + 3 * SL];
    const float p1 = *p1p;

    #pragma unroll
    for (int qq = 0; qq < 4; ++qq) {
        f32x4 hv = cw[qq * 4 + 0] * u0 + cw[qq * 4 + 1] * u1 +
                   cw[qq * 4 + 2] * u2 + cw[qq * 4 + 3] * u3;
        const float bq = cb[qq];
        f32x4 ho;
        #pragma unroll
        for (int j = 0; j < 4; ++j) {
            const float v = hv[j] + bq;
            ho[j] = v >= 0.f ? v : p1 * v;
        }
        *(f32x4*)&H[qq * SL + base] = ho;
    }
}

extern "C" void kernel_launch(void* const* d_in, const int* in_sizes, int n_in,
                              void* d_out, int out_size, void* d_ws, size_t ws_size,
                              hipStream_t stream)
{
    const float* theta = (const float*)d_in[0];
    const float* tt    = (const float*)d_in[1];
    const float* a     = (const float*)d_in[2];
    const float* x     = (const float*)d_in[3];
    const float* fcw   = (const float*)d_in[4];
    const float* fcb   = (const float*)d_in[5];
    const float* cw    = (const float*)d_in[6];
    const float* cb    = (const float*)d_in[7];
    const float* p0    = (const float*)d_in[8];
    const float* p1    = (const float*)d_in[9];

    float* out = (float*)d_out;
    float* H = out;                              // output 0: h  [R,N,DO]
    float* U = out + (size_t)R_ * N_ * DO_;      // output 1: u  [R,N,DO]

    const size_t ybytes = (size_t)R_ * DO_ * N_ * sizeof(__bf16);
    __bf16* Y = (ws_size >= ybytes) ? (__bf16*)d_ws : (__bf16*)H;

    k_prep<<<dim3(256), dim3(256), 0, stream>>>(theta, tt, x, fcw, Y);
    k_diff<<<dim3(1024), dim3(256), 0, stream>>>(a, Y, fcb, p0, U);
    k_conv<<<dim3(256), dim3(256), 0, stream>>>(U, cw, cb, p1, H);
}

// Round 5
// 61.003 us; speedup vs baseline: 1.7741x; 1.1980x over previous
//
#include <hip/hip_runtime.h>
#include <hip/hip_bf16.h>
#include <stddef.h>

#define R_ 4
#define J_ 6
#define N_ 4096
#define DI_ 128
#define DO_ 64

typedef __bf16 bf16x8 __attribute__((ext_vector_type(8)));
typedef __bf16 bf16x4 __attribute__((ext_vector_type(4)));
typedef float f32x4 __attribute__((ext_vector_type(4)));

static __device__ __forceinline__ bf16x8 cvt8(f32x4 a, f32x4 b) {
    bf16x8 r;
    r[0] = (__bf16)a[0]; r[1] = (__bf16)a[1]; r[2] = (__bf16)a[2]; r[3] = (__bf16)a[3];
    r[4] = (__bf16)b[0]; r[5] = (__bf16)b[1]; r[6] = (__bf16)b[2]; r[7] = (__bf16)b[3];
    return r;
}

// ---------------------------------------------------------------------------
// Kernel 1 (unchanged, verified): y as pre-packed MFMA B-fragments:
//   Yf[r][kb=m>>5][ot=o>>4][lane=(o&15)+16*((m&31)>>3)][j=m&7]   (bf16)
// ---------------------------------------------------------------------------
__global__ __launch_bounds__(256) void k_prep(const float* __restrict__ theta,
                                              const float* __restrict__ tt,
                                              const float* __restrict__ x,
                                              const float* __restrict__ fcw,
                                              __bf16* __restrict__ Yf)
{
    const int b = blockIdx.x;
    const int r = b >> 6;
    const int m0 = (b & 63) << 6;
    const int tid = threadIdx.x;
    const int w = tid >> 6, l = tid & 63, lg = l >> 4, lr = l & 15;

    float coef = 0.f;
    #pragma unroll
    for (int j = 0; j < J_; ++j) coef += theta[r * J_ + j] * tt[r * J_ + j];

    const float* wp  = fcw + ((size_t)r * DO_ + w * 16 + lr) * DI_ + lg * 8;
    const float* xp0 = x   + ((size_t)r * N_  + m0     + lr) * DI_ + lg * 8;

    f32x4 acc[4];
    #pragma unroll
    for (int mt = 0; mt < 4; ++mt) acc[mt] = (f32x4)0.0f;

    #pragma unroll
    for (int s = 0; s < 4; ++s) {
        bf16x8 af = cvt8(*(const f32x4*)(wp + s * 32), *(const f32x4*)(wp + s * 32 + 4));
        #pragma unroll
        for (int mt = 0; mt < 4; ++mt) {
            const float* xp = xp0 + (size_t)mt * 16 * DI_ + s * 32;
            bf16x8 bf = cvt8(*(const f32x4*)xp, *(const f32x4*)(xp + 4));
            acc[mt] = __builtin_amdgcn_mfma_f32_16x16x32_bf16(af, bf, acc[mt], 0, 0, 0);
        }
    }

    __bf16* Yr = Yf + (size_t)r * (DO_ * N_);
    #pragma unroll
    for (int mt = 0; mt < 4; ++mt) {
        const int kb = (m0 >> 5) + (mt >> 1);
        const int hi = ((mt & 1) << 1) + (lr >> 3);
        const int j  = lr & 7;
        #pragma unroll
        for (int i = 0; i < 4; ++i) {
            const int lanep = lg * 4 + i + (hi << 4);
            Yr[((size_t)(kb * 4 + w) * 64 + lanep) * 8 + j] = (__bf16)(coef * acc[mt][i]);
        }
    }
}

// ---------------------------------------------------------------------------
// Kernel 2: u[r][n][o] = prelu( sum_m a[r][n][m] * y[r][m][o] + fc_b[r][o] )
// 32 n-rows per block (512 blocks): each wave owns its K-quarter and computes
// TWO 16-row tiles, holding each Y fragment in registers across both -> Y
// global traffic halves (512->256MB), MFMA:VMEM doubles. A-path staging
// identical to round 4 (4-row x 256B coalesced loads, bf16 cvt at staging,
// XOR-swizzled wave-private LDS, no barriers). Accumulation order per output
// unchanged -> bit-identical results to rounds 3/4.
// ---------------------------------------------------------------------------
__global__ __launch_bounds__(256, 2) void k_diff(const float* __restrict__ A,
                                                 const __bf16* __restrict__ Yf,
                                                 const float* __restrict__ fcb,
                                                 const float* __restrict__ p0p,
                                                 float* __restrict__ U)
{
    const int b = blockIdx.x;
    const int r = b >> 7;
    const int n0 = (b & 127) << 5;
    const int tid = threadIdx.x;
    const int w = tid >> 6, l = tid & 63, lg = l >> 4, lr = l & 15;

    __shared__ __bf16 abuf[4][32 * 64];            // 4KB per wave, swizzled
    __shared__ __align__(16) float red[4][32][68]; // K-split reduction

    const int srow = l >> 4;            // 0..3
    const int scol = (l & 15) * 4;      // float col within the 64-float chunk
    const float* Abl = A + ((size_t)r * N_ + n0 + srow) * N_ + w * 1024 + scol;

    // LDS write offsets (bf16 elems), byte ^ (row&7)<<4 involution
    int wo[8];
    #pragma unroll
    for (int j = 0; j < 8; ++j) {
        const int row = 4 * j + srow;
        wo[j] = row * 64 + (((scol * 2) ^ ((row & 7) << 4)) >> 1);
    }
    // LDS read offsets: row = nt*16 + lr (row&7 == lr&7)
    const int q = (lr & 7) << 4;
    int ro[2][2];
    #pragma unroll
    for (int nt = 0; nt < 2; ++nt)
        #pragma unroll
        for (int ss = 0; ss < 2; ++ss)
            ro[nt][ss] = (nt * 16 + lr) * 64 + (((ss * 64 + lg * 16) ^ q) >> 1);

    const __bf16* yb0 = Yf + (size_t)r * (DO_ * N_) + (size_t)w * 32 * 2048 + (size_t)l * 8;

    f32x4 acc[2][4];
    #pragma unroll
    for (int nt = 0; nt < 2; ++nt)
        #pragma unroll
        for (int ot = 0; ot < 4; ++ot) acc[nt][ot] = (f32x4)0.0f;

    // prologue: load chunk 0
    f32x4 rg[8];
    #pragma unroll
    for (int j = 0; j < 8; ++j)
        rg[j] = *(const f32x4*)(Abl + (size_t)(4 * j) * N_);

    #pragma unroll 2
    for (int c = 0; c < 16; ++c) {
        // stage chunk c (cvt + swizzled ds_write_b64)
        #pragma unroll
        for (int j = 0; j < 8; ++j) {
            bf16x4 cv;
            cv[0] = (__bf16)rg[j][0]; cv[1] = (__bf16)rg[j][1];
            cv[2] = (__bf16)rg[j][2]; cv[3] = (__bf16)rg[j][3];
            *(bf16x4*)&abuf[w][wo[j]] = cv;
        }
        // prefetch chunk c+1
        if (c < 15) {
            #pragma unroll
            for (int j = 0; j < 8; ++j)
                rg[j] = *(const f32x4*)(Abl + (size_t)(4 * j) * N_ + (c + 1) * 64);
        }
        // compute both row-tiles, Y fragments held in regs across nt
        #pragma unroll
        for (int ss = 0; ss < 2; ++ss) {
            const __bf16* yb = yb0 + (size_t)(c * 2 + ss) * 2048;
            bf16x8 bfr[4];
            #pragma unroll
            for (int ot = 0; ot < 4; ++ot)
                bfr[ot] = *(const bf16x8*)(yb + (size_t)ot * 512);
            #pragma unroll
            for (int nt = 0; nt < 2; ++nt) {
                bf16x8 af = *(const bf16x8*)&abuf[w][ro[nt][ss]];
                #pragma unroll
                for (int ot = 0; ot < 4; ++ot)
                    acc[nt][ot] = __builtin_amdgcn_mfma_f32_16x16x32_bf16(af, bfr[ot], acc[nt][ot], 0, 0, 0);
            }
        }
    }

    // K-split reduction in LDS (round-3 pattern, 32 rows)
    #pragma unroll
    for (int nt = 0; nt < 2; ++nt)
        #pragma unroll
        for (int ot = 0; ot < 4; ++ot)
            #pragma unroll
            for (int i = 0; i < 4; ++i)
                red[w][nt * 16 + lg * 4 + i][ot * 16 + lr] = acc[nt][ot][i];
    __syncthreads();

    const float p0 = *p0p;
    #pragma unroll
    for (int idx = tid; idx < 512; idx += 256) {
        const int n = idx >> 4;
        const int o = (idx & 15) << 2;
        f32x4 s4 = *(const f32x4*)&red[0][n][o];
        #pragma unroll
        for (int w2 = 1; w2 < 4; ++w2)
            s4 += *(const f32x4*)&red[w2][n][o];
        f32x4 uv;
        #pragma unroll
        for (int j = 0; j < 4; ++j) {
            const float v = s4[j] + fcb[r * DO_ + o + j];
            uv[j] = v >= 0.f ? v : p0 * v;
        }
        *(f32x4*)&U[((size_t)r * N_ + n0 + n) * DO_ + o] = uv;
    }
}

// ---------------------------------------------------------------------------
// Kernel 3 (unchanged): h = prelu(conv_w @ u + conv_b)
// ---------------------------------------------------------------------------
__global__ __launch_bounds__(256) void k_conv(const float* __restrict__ U,
                                              const float* __restrict__ cw,
                                              const float* __restrict__ cb,
                                              const float* __restrict__ p1p,
                                              float* __restrict__ H)
{
    const size_t t = (size_t)blockIdx.x * 256 + threadIdx.x;
    const size_t base = t * 4;
    const size_t SL = (size_t)N_ * DO_;  // 262144

    f32x4 u0 = *(const f32x4*)&U[base];
    f32x4 u1 = *(const f32x4*)&U[base + SL];
    f32x4 u2 = *(const f32x4*)&U[base + 2 * SL];
    f32x4 u3 = *(const f32x4*)&U[base + 3 * SL];
    const float p1 = *p1p;

    #pragma unroll
    for (int qq = 0; qq < 4; ++qq) {
        f32x4 hv = cw[qq * 4 + 0] * u0 + cw[qq * 4 + 1] * u1 +
                   cw[qq * 4 + 2] * u2 + cw[qq * 4 + 3] * u3;
        const float bq = cb[qq];
        f32x4 ho;
        #pragma unroll
        for (int j = 0; j < 4; ++j) {
            const float v = hv[j] + bq;
            ho[j] = v >= 0.f ? v : p1 * v;
        }
        *(f32x4*)&H[qq * SL + base] = ho;
    }
}

extern "C" void kernel_launch(void* const* d_in, const int* in_sizes, int n_in,
                              void* d_out, int out_size, void* d_ws, size_t ws_size,
                              hipStream_t stream)
{
    const float* theta = (const float*)d_in[0];
    const float* tt    = (const float*)d_in[1];
    const float* a     = (const float*)d_in[2];
    const float* x     = (const float*)d_in[3];
    const float* fcw   = (const float*)d_in[4];
    const float* fcb   = (const float*)d_in[5];
    const float* cw    = (const float*)d_in[6];
    const float* cb    = (const float*)d_in[7];
    const float* p0    = (const float*)d_in[8];
    const float* p1    = (const float*)d_in[9];

    float* out = (float*)d_out;
    float* H = out;                              // output 0: h  [R,N,DO]
    float* U = out + (size_t)R_ * N_ * DO_;      // output 1: u  [R,N,DO]

    const size_t ybytes = (size_t)R_ * DO_ * N_ * sizeof(__bf16);
    __bf16* Y = (ws_size >= ybytes) ? (__bf16*)d_ws : (__bf16*)H;

    k_prep<<<dim3(256), dim3(256), 0, stream>>>(theta, tt, x, fcw, Y);
    k_diff<<<dim3(512), dim3(256), 0, stream>>>(a, Y, fcb, p0, U);
    k_conv<<<dim3(256), dim3(256), 0, stream>>>(U, cw, cb, p1, H);
}